// Round 1
// baseline (884.138 us; speedup 1.0000x reference)
//
#include <hip/hip_runtime.h>

#define TPB 256
constexpr int HID = 16;
constexpr int NC  = 8;

// ---- fp32 atomic add via native global_atomic_add_f32 ----
__device__ __forceinline__ void atomAddF(float* p, float v) {
    unsafeAtomicAdd(p, v);
}

// Detect whether edge_index arrived as int64 (little-endian: odd 32-bit words
// are the high halves, all zero since 0 <= idx < 100000) or int32.
__global__ void detect64_kernel(const int* __restrict__ ei, int E, int* flag) {
    int l = threadIdx.x;
    int v = 0;
    if (l < 32 && 2 * l + 1 < 2 * E) v = ei[2 * l + 1];
    unsigned long long b = __ballot(v != 0);
    if (l == 0) *flag = (b == 0ULL) ? 1 : 0;
}

// Load edge endpoint: index = row*E + e (row 0 = src, row 1 = dst).
__device__ __forceinline__ int edge_at(const int* __restrict__ ei, int index, int is64) {
    return is64 ? ei[2 * index] : ei[index];
}

// deg[i] = 1.0 (self-loop weight)
__global__ void init_deg_kernel(float* deg, int N) {
    int i = blockIdx.x * TPB + threadIdx.x;
    if (i < N) deg[i] = 1.0f;
}

__global__ void deg_edge_kernel(const int* __restrict__ ei, const float* __restrict__ w,
                                float* deg, int E, const int* __restrict__ flag) {
    int e = blockIdx.x * TPB + threadIdx.x;
    if (e >= E) return;
    int is64 = *flag;
    int dst = edge_at(ei, E + e, is64);
    atomAddF(&deg[dst], w[e]);
}

// in-place deg -> deg^{-1/2}  (deg >= 1 always, self-loop)
__global__ void dis_kernel(float* deg, int N) {
    int i = blockIdx.x * TPB + threadIdx.x;
    if (i < N) deg[i] = rsqrtf(deg[i]);
}

// h1 = x @ W1   (N x K) @ (K x 16), one row per thread.
// W indices are wave-uniform -> scalar loads; x rows read sequentially (line reuse over k).
__global__ void gemm1_kernel(const float* __restrict__ x, const float* __restrict__ W,
                             float* __restrict__ h, int N, int K) {
    int row = blockIdx.x * TPB + threadIdx.x;
    if (row >= N) return;
    const float* xr = x + (size_t)row * K;
    float acc[HID];
#pragma unroll
    for (int j = 0; j < HID; ++j) acc[j] = 0.f;
    for (int k = 0; k < K; k += 4) {
        float4 xv = *reinterpret_cast<const float4*>(xr + k);
        const float* Wk = W + (size_t)k * HID;
#pragma unroll
        for (int kk = 0; kk < 4; ++kk) {
            float xs = (&xv.x)[kk];
#pragma unroll
            for (int j = 0; j < HID; ++j)
                acc[j] = fmaf(xs, Wk[kk * HID + j], acc[j]);
        }
    }
    float* hr = h + (size_t)row * HID;
#pragma unroll
    for (int j = 0; j < HID; j += 4)
        *reinterpret_cast<float4*>(hr + j) = make_float4(acc[j], acc[j+1], acc[j+2], acc[j+3]);
}

// agg1 = b1 + dis^2 * h1   (self-loop contribution + bias)
__global__ void init_agg1_kernel(const float* __restrict__ h1, const float* __restrict__ dis,
                                 const float* __restrict__ b1, float* __restrict__ agg1, int N) {
    int t = blockIdx.x * TPB + threadIdx.x;
    if (t >= N * HID) return;
    int i = t >> 4, j = t & 15;
    float d = dis[i];
    agg1[t] = b1[j] + d * d * h1[t];
}

// one thread per (edge, j) : agg1[dst][j] += norm_e * h1[src][j]
__global__ void edge1_kernel(const int* __restrict__ ei, const float* __restrict__ w,
                             const float* __restrict__ dis, const float* __restrict__ h1,
                             float* __restrict__ agg1, int E, const int* __restrict__ flag) {
    int t = blockIdx.x * TPB + threadIdx.x;
    if (t >= E * HID) return;
    int e = t >> 4, j = t & 15;
    int is64 = *flag;
    int src = edge_at(ei, e, is64);
    int dst = edge_at(ei, E + e, is64);
    float nrm = dis[src] * w[e] * dis[dst];
    atomAddF(&agg1[dst * HID + j], nrm * h1[src * HID + j]);
}

// h2 = relu(agg1) @ W2   (N x 16) @ (16 x 8)
__global__ void gemm2_kernel(const float* __restrict__ agg1, const float* __restrict__ W2,
                             float* __restrict__ h2, int N) {
    int i = blockIdx.x * TPB + threadIdx.x;
    if (i >= N) return;
    const float* a = agg1 + (size_t)i * HID;
    float hv[HID];
#pragma unroll
    for (int k = 0; k < HID; k += 4) {
        float4 v = *reinterpret_cast<const float4*>(a + k);
        hv[k]     = fmaxf(v.x, 0.f);
        hv[k + 1] = fmaxf(v.y, 0.f);
        hv[k + 2] = fmaxf(v.z, 0.f);
        hv[k + 3] = fmaxf(v.w, 0.f);
    }
    float acc[NC];
#pragma unroll
    for (int c = 0; c < NC; ++c) acc[c] = 0.f;
#pragma unroll
    for (int k = 0; k < HID; ++k)
#pragma unroll
        for (int c = 0; c < NC; ++c)
            acc[c] = fmaf(hv[k], W2[k * NC + c], acc[c]);
    float* o = h2 + (size_t)i * NC;
    *reinterpret_cast<float4*>(o)     = make_float4(acc[0], acc[1], acc[2], acc[3]);
    *reinterpret_cast<float4*>(o + 4) = make_float4(acc[4], acc[5], acc[6], acc[7]);
}

// out = b2 + dis^2 * h2   (self-loop + bias), accumulated directly in d_out
__global__ void init_out_kernel(const float* __restrict__ h2, const float* __restrict__ dis,
                                const float* __restrict__ b2, float* __restrict__ out, int N) {
    int t = blockIdx.x * TPB + threadIdx.x;
    if (t >= N * NC) return;
    int i = t >> 3, j = t & 7;
    float d = dis[i];
    out[t] = b2[j] + d * d * h2[t];
}

__global__ void edge2_kernel(const int* __restrict__ ei, const float* __restrict__ w,
                             const float* __restrict__ dis, const float* __restrict__ h2,
                             float* __restrict__ out, int E, const int* __restrict__ flag) {
    int t = blockIdx.x * TPB + threadIdx.x;
    if (t >= E * NC) return;
    int e = t >> 3, j = t & 7;
    int is64 = *flag;
    int src = edge_at(ei, e, is64);
    int dst = edge_at(ei, E + e, is64);
    float nrm = dis[src] * w[e] * dis[dst];
    atomAddF(&out[dst * NC + j], nrm * h2[src * NC + j]);
}

// in-place log_softmax over 8 classes, one row per thread
__global__ void lsm_kernel(float* __restrict__ out, int N) {
    int i = blockIdx.x * TPB + threadIdx.x;
    if (i >= N) return;
    float* r = out + (size_t)i * NC;
    float4 a = *reinterpret_cast<const float4*>(r);
    float4 b = *reinterpret_cast<const float4*>(r + 4);
    float v[NC] = {a.x, a.y, a.z, a.w, b.x, b.y, b.z, b.w};
    float m = v[0];
#pragma unroll
    for (int j = 1; j < NC; ++j) m = fmaxf(m, v[j]);
    float s = 0.f;
#pragma unroll
    for (int j = 0; j < NC; ++j) s += expf(v[j] - m);
    float lse = m + logf(s);
#pragma unroll
    for (int j = 0; j < NC; ++j) v[j] -= lse;
    *reinterpret_cast<float4*>(r)     = make_float4(v[0], v[1], v[2], v[3]);
    *reinterpret_cast<float4*>(r + 4) = make_float4(v[4], v[5], v[6], v[7]);
}

extern "C" void kernel_launch(void* const* d_in, const int* in_sizes, int n_in,
                              void* d_out, int out_size, void* d_ws, size_t ws_size,
                              hipStream_t stream) {
    const float* x  = (const float*)d_in[0];
    const int*   ei = (const int*)d_in[1];
    const float* w  = (const float*)d_in[2];
    const float* W1 = (const float*)d_in[3];
    const float* b1 = (const float*)d_in[4];
    const float* W2 = (const float*)d_in[5];
    const float* b2 = (const float*)d_in[6];
    float* out = (float*)d_out;

    int E = in_sizes[2];          // 3,200,000
    int N = out_size / NC;        // 100,000
    int K = in_sizes[0] / N;      // 512

    float* deg  = (float*)d_ws;                 // N  (becomes dis in-place)
    float* h1   = deg + N;                      // N*16
    float* agg1 = h1 + (size_t)N * HID;         // N*16
    float* h2   = agg1 + (size_t)N * HID;       // N*8
    int*   flag = (int*)(h2 + (size_t)N * NC);  // 1

    auto nb = [](long long n) { return (int)((n + TPB - 1) / TPB); };

    detect64_kernel<<<1, 64, 0, stream>>>(ei, E, flag);
    init_deg_kernel<<<nb(N), TPB, 0, stream>>>(deg, N);
    deg_edge_kernel<<<nb(E), TPB, 0, stream>>>(ei, w, deg, E, flag);
    dis_kernel<<<nb(N), TPB, 0, stream>>>(deg, N);
    gemm1_kernel<<<nb(N), TPB, 0, stream>>>(x, W1, h1, N, K);
    init_agg1_kernel<<<nb((long long)N * HID), TPB, 0, stream>>>(h1, deg, b1, agg1, N);
    edge1_kernel<<<nb((long long)E * HID), TPB, 0, stream>>>(ei, w, deg, h1, agg1, E, flag);
    gemm2_kernel<<<nb(N), TPB, 0, stream>>>(agg1, W2, h2, N);
    init_out_kernel<<<nb((long long)N * NC), TPB, 0, stream>>>(h2, deg, b2, out, N);
    edge2_kernel<<<nb((long long)E * NC), TPB, 0, stream>>>(ei, w, deg, h2, out, E, flag);
    lsm_kernel<<<nb(N), TPB, 0, stream>>>(out, N);
}